// Round 6
// baseline (141.660 us; speedup 1.0000x reference)
//
#include <hip/hip_runtime.h>
#include <math.h>

#define NNODES 4096
#define CC     128
#define KCL    32
#define MM     128
#define EE     65536
#define HH     8
#define DD     64
#define INNERD 512

typedef __attribute__((ext_vector_type(8))) short short8;
typedef __attribute__((ext_vector_type(4))) float f32x4;

__device__ __forceinline__ float bf2f(ushort u) { return __uint_as_float(((unsigned)u) << 16); }
__device__ __forceinline__ ushort f2bf(float f) {
  unsigned b = __float_as_uint(f);
  return (ushort)((b + 0x7FFFu + ((b >> 16) & 1u)) >> 16);
}

// ================= pre: tiled W transposes + e01 + rotary tables + adj zero + LN1 ====
__global__ __launch_bounds__(256) void pre_kernel(const float* __restrict__ Wq,
                                                  const float* __restrict__ Wkv,
                                                  const float* __restrict__ Wo,
                                                  const float* __restrict__ W1,
                                                  const float* __restrict__ W2,
                                                  const float* __restrict__ adj_emb,
                                                  const float* __restrict__ We,
                                                  const float* __restrict__ be,
                                                  const float* __restrict__ x,
                                                  const int* __restrict__ cl,
                                                  const float* __restrict__ ln1g,
                                                  const float* __restrict__ ln1b,
                                                  ushort* __restrict__ WqkvT,
                                                  ushort* __restrict__ WoT,
                                                  ushort* __restrict__ W1T,
                                                  ushort* __restrict__ W2T,
                                                  float* __restrict__ e01,
                                                  float* __restrict__ cosF,
                                                  float* __restrict__ sinF,
                                                  unsigned* __restrict__ adjw,
                                                  ushort* __restrict__ y) {
  __shared__ float lds[32][33];
  int bid = blockIdx.x, t = threadIdx.x;
  if (bid < 384) {
    const float* src; ushort* dst; int N, K, tile;
    if (bid < 64)        { src = Wq;  dst = WqkvT;             N = 512;  K = 128; tile = bid; }
    else if (bid < 192)  { src = Wkv; dst = WqkvT + 512 * 128; N = 1024; K = 128; tile = bid - 64; }
    else if (bid < 256)  { src = Wo;  dst = WoT;               N = 128;  K = 512; tile = bid - 192; }
    else if (bid < 320)  { src = W1;  dst = W1T;               N = 512;  K = 128; tile = bid - 256; }
    else                 { src = W2;  dst = W2T;               N = 128;  K = 512; tile = bid - 320; }
    int tilesN = N >> 5;
    int k0 = (tile / tilesN) << 5, n0 = (tile % tilesN) << 5;
#pragma unroll
    for (int i = 0; i < 4; ++i) {
      int idx = i * 256 + t, kk = idx >> 5, nn = idx & 31;
      lds[kk][nn] = src[(size_t)(k0 + kk) * N + n0 + nn];
    }
    __syncthreads();
#pragma unroll
    for (int i = 0; i < 4; ++i) {
      int idx = i * 256 + t, nn = idx >> 5, kk = idx & 31;
      dst[(size_t)(n0 + nn) * K + k0 + kk] = f2bf(lds[kk][nn]);
    }
  } else if (bid < 388) {
    int idx = (bid - 384) * 256 + t;  // 0..1023
    int which = idx >> 9, col = idx & 511;
    float a = 0.f;
    for (int c = 0; c < CC; ++c) a += adj_emb[which * CC + c] * We[(size_t)c * INNERD + col];
    e01[idx] = a + be[col];
  } else if (bid < 396) {
#pragma unroll
    for (int e = 0; e < 4; ++e) {
      int idx = ((bid - 388) * 256 + t) * 4 + e;  // 0..8191
      int i = idx >> 6, d = idx & 63, p = d >> 1;
      float inv = exp2f(-(float)p * (13.287712379549449f / 32.0f)); // 10000^(-p/32)
      float ang = (float)i * inv;
      cosF[idx] = cosf(ang);
      sinF[idx] = sinf(ang);
    }
  } else if (bid < 400) {
    int base = ((bid - 396) * 256 + t) * 16;
#pragma unroll
    for (int e = 0; e < 16; ++e) adjw[base + e] = 0u;
  } else {
    int row = (bid - 400) * 4 + (t >> 6);
    int lane = t & 63;
    int src = cl[row];
    const float* p = x + (size_t)src * CC;
    float2 v = *(const float2*)(p + lane * 2);
    float s = v.x + v.y, q = v.x * v.x + v.y * v.y;
#pragma unroll
    for (int o = 32; o; o >>= 1) { s += __shfl_xor(s, o); q += __shfl_xor(q, o); }
    float mu = s * (1.0f / CC);
    float var = q * (1.0f / CC) - mu * mu;
    float rs = rsqrtf(var + 1e-5f);
    float2 g2 = *(const float2*)(ln1g + lane * 2);
    float2 b2 = *(const float2*)(ln1b + lane * 2);
    float ox = (v.x - mu) * rs * g2.x + b2.x;
    float oy = (v.y - mu) * rs * g2.y + b2.y;
    *(unsigned*)&y[(size_t)row * CC + lane * 2] = (unsigned)f2bf(ox) | ((unsigned)f2bf(oy) << 16);
  }
}

// ========== QKV GEMM (fused rotary) + adjacency build (extra blocks) ==========
__global__ __launch_bounds__(256) void qkv_adj_kernel(const ushort* __restrict__ A,
                                                      const ushort* __restrict__ BT,
                                                      const float* __restrict__ bq,
                                                      const float* __restrict__ bkv,
                                                      const float* __restrict__ cosF,
                                                      const float* __restrict__ sinF,
                                                      const int* __restrict__ ei,
                                                      unsigned* __restrict__ adjw,
                                                      ushort* __restrict__ P) {
  __shared__ __align__(16) ushort Ab[128 * 32];
  __shared__ __align__(16) ushort Bb[128 * 32];
  int bid = blockIdx.x, t = threadIdx.x;
  if (bid >= 384) {
    int e = (bid - 384) * 256 + t;
    int s = ei[e], d = ei[EE + e];
    int cs = s >> 7, cd = d >> 7;
    if (cs == cd) {
      int flat = cs * (MM * MM) + (s & 127) * MM + (d & 127);
      atomicOr(adjw + (flat >> 5), 1u << (flat & 31));
    }
    return;
  }
  int w = t >> 6, l = t & 63;
  int nt = bid % 12, mt = bid / 12;
  int n0 = nt * 128, m0 = mt * 128;
  int wr = (w >> 1) * 64, wc = (w & 1) * 64;
  f32x4 acc[4][4];
#pragma unroll
  for (int mi = 0; mi < 4; ++mi)
#pragma unroll
    for (int nj = 0; nj < 4; ++nj) acc[mi][nj] = (f32x4){0.f, 0.f, 0.f, 0.f};

  for (int k0 = 0; k0 < 128; k0 += 32) {
#pragma unroll
    for (int i = 0; i < 2; ++i) {
      int c = t + i * 256;
      int r = c >> 2, kc = c & 3;
      *(uint4*)&Ab[r * 32 + kc * 8] = *(const uint4*)&A[(size_t)(m0 + r) * 128 + k0 + kc * 8];
      *(uint4*)&Bb[r * 32 + kc * 8] = *(const uint4*)&BT[(size_t)(n0 + r) * 128 + k0 + kc * 8];
    }
    __syncthreads();
    short8 aF[4], bF[4];
#pragma unroll
    for (int mi = 0; mi < 4; ++mi) aF[mi] = *(const short8*)&Ab[(wr + mi * 16 + (l & 15)) * 32 + (l >> 4) * 8];
#pragma unroll
    for (int nj = 0; nj < 4; ++nj) bF[nj] = *(const short8*)&Bb[(wc + nj * 16 + (l & 15)) * 32 + (l >> 4) * 8];
#pragma unroll
    for (int mi = 0; mi < 4; ++mi)
#pragma unroll
      for (int nj = 0; nj < 4; ++nj)
        acc[mi][nj] = __builtin_amdgcn_mfma_f32_16x16x32_bf16(aF[mi], bF[nj], acc[mi][nj], 0, 0, 0);
    __syncthreads();
  }
#pragma unroll
  for (int mi = 0; mi < 4; ++mi)
#pragma unroll
    for (int nj = 0; nj < 4; ++nj)
#pragma unroll
      for (int r = 0; r < 4; ++r) {
        int m = m0 + wr + mi * 16 + ((l >> 4) << 2) + r;
        int n = n0 + wc + nj * 16 + (l & 15);
        float bias = n < 512 ? bq[n] : bkv[n - 512];
        float v = acc[mi][nj][r] + bias;
        float partner = __shfl_xor(v, 1);
        if (n < 1024) {
          int d = n & 63, i = m & 127;
          float cv = cosF[i * 64 + d], sv = sinF[i * 64 + d];
          v = (n & 1) ? (v * cv + partner * sv) : (v * cv - partner * sv);
        }
        P[(size_t)m * 1536 + n] = f2bf(v);
      }
}

// ---------------- fused MFMA attention per (cluster, head), 512 threads ----------------
__global__ __launch_bounds__(512) void attn_kernel(const ushort* __restrict__ P,
                                                   const unsigned* __restrict__ adjw,
                                                   const float* __restrict__ e01,
                                                   ushort* __restrict__ AO) {
  __shared__ __align__(16) ushort QKP[2 * 128 * 64];  // Qb | Kb ; Pl overlays both
  __shared__ __align__(16) ushort VT[64 * 128];
  __shared__ unsigned adjL[512];
  __shared__ float e0s[64], e1s[64], qe0L[128], qe1L[128], sL[128];
  ushort* Qb = QKP;
  ushort* Kb = QKP + 8192;
  ushort* Pl = QKP;

  int t = threadIdx.x, w = t >> 6, l = t & 63;
  int kc = blockIdx.x >> 3, h = blockIdx.x & 7;

  const ushort* qg = P + (size_t)kc * 128 * 1536 + h * DD;

  for (int c = t; c < 1024; c += 512) {
    int r = c >> 3, ch = c & 7;
    uint4 qv = *(const uint4*)&qg[(size_t)r * 1536 + ch * 8];
    *(uint4*)&Qb[r * 64 + ((ch ^ (r & 7)) << 3)] = qv;
    uint4 kv = *(const uint4*)&qg[(size_t)r * 1536 + 512 + ch * 8];
    *(uint4*)&Kb[r * 64 + ((ch ^ (r & 7)) << 3)] = kv;
    uint4 vv = *(const uint4*)&qg[(size_t)r * 1536 + 1024 + ch * 8];
    const ushort* vp = (const ushort*)&vv;
#pragma unroll
    for (int e = 0; e < 8; ++e) {
      int d = ch * 8 + e;
      VT[d * 128 + (((r >> 3) ^ (d & 7)) << 3) + (r & 7)] = vp[e];
    }
  }
  adjL[t & 511] = adjw[kc * 512 + (t & 511)];
  if (t < 64) { e0s[t] = e01[h * DD + t]; e1s[t] = e01[512 + h * DD + t]; }
  __syncthreads();

  {
    int row = t >> 2, part = t & 3;
    float a0 = 0.f, a1 = 0.f;
#pragma unroll
    for (int dd = 0; dd < 16; ++dd) {
      int d = part * 16 + dd;
      float qv = bf2f(Qb[row * 64 + (((d >> 3) ^ (row & 7)) << 3) + (d & 7)]);
      a0 += qv * e0s[d]; a1 += qv * e1s[d];
    }
    a0 += __shfl_xor(a0, 1); a0 += __shfl_xor(a0, 2);
    a1 += __shfl_xor(a1, 1); a1 += __shfl_xor(a1, 2);
    if (part == 0) { qe0L[row] = a0; qe1L[row] = a1; }
  }
  __syncthreads();

  int m0 = w * 16;
  f32x4 s_acc[8];
#pragma unroll
  for (int nj = 0; nj < 8; ++nj) s_acc[nj] = (f32x4){0.f, 0.f, 0.f, 0.f};
  {
    int arow = m0 + (l & 15);
    short8 aF0 = *(const short8*)&Qb[arow * 64 + ((((l >> 4)) ^ (arow & 7)) << 3)];
    short8 aF1 = *(const short8*)&Qb[arow * 64 + (((4 + (l >> 4)) ^ (arow & 7)) << 3)];
#pragma unroll
    for (int nj = 0; nj < 8; ++nj) {
      int brow = nj * 16 + (l & 15);
      short8 b0 = *(const short8*)&Kb[brow * 64 + ((((l >> 4)) ^ (brow & 7)) << 3)];
      short8 b1 = *(const short8*)&Kb[brow * 64 + (((4 + (l >> 4)) ^ (brow & 7)) << 3)];
      s_acc[nj] = __builtin_amdgcn_mfma_f32_16x16x32_bf16(aF0, b0, s_acc[nj], 0, 0, 0);
      s_acc[nj] = __builtin_amdgcn_mfma_f32_16x16x32_bf16(aF1, b1, s_acc[nj], 0, 0, 0);
    }
  }

  float mrow[4], ssum[4], sadj[4];
#pragma unroll
  for (int r = 0; r < 4; ++r) {
    int i = m0 + ((l >> 4) << 2) + r;
    float q0 = qe0L[i], q1 = qe1L[i];
    unsigned w0 = adjL[i * 4 + 0], w1 = adjL[i * 4 + 1], w2 = adjL[i * 4 + 2], w3 = adjL[i * 4 + 3];
    float mx = -1e30f;
#pragma unroll
    for (int nj = 0; nj < 8; ++nj) {
      unsigned word = (nj >> 1) == 0 ? w0 : (nj >> 1) == 1 ? w1 : (nj >> 1) == 2 ? w2 : w3;
      unsigned bit = (word >> (((nj & 1) << 4) + (l & 15))) & 1u;
      float s = (s_acc[nj][r] + (bit ? q1 : q0)) * 0.125f;
      s_acc[nj][r] = s;
      mx = fmaxf(mx, s);
    }
    mrow[r] = mx;
  }
#pragma unroll
  for (int o = 1; o < 16; o <<= 1)
#pragma unroll
    for (int r = 0; r < 4; ++r) mrow[r] = fmaxf(mrow[r], __shfl_xor(mrow[r], o));
#pragma unroll
  for (int r = 0; r < 4; ++r) {
    float sum = 0.f;
#pragma unroll
    for (int nj = 0; nj < 8; ++nj) {
      float p = __expf(s_acc[nj][r] - mrow[r]);
      s_acc[nj][r] = p;
      sum += p;
    }
    ssum[r] = sum;
  }
#pragma unroll
  for (int o = 1; o < 16; o <<= 1)
#pragma unroll
    for (int r = 0; r < 4; ++r) ssum[r] += __shfl_xor(ssum[r], o);
#pragma unroll
  for (int r = 0; r < 4; ++r) {
    int i = m0 + ((l >> 4) << 2) + r;
    unsigned w0 = adjL[i * 4 + 0], w1 = adjL[i * 4 + 1], w2 = adjL[i * 4 + 2], w3 = adjL[i * 4 + 3];
    float inv = 1.0f / ssum[r];
    float sa = 0.f;
#pragma unroll
    for (int nj = 0; nj < 8; ++nj) {
      unsigned word = (nj >> 1) == 0 ? w0 : (nj >> 1) == 1 ? w1 : (nj >> 1) == 2 ? w2 : w3;
      unsigned bit = (word >> (((nj & 1) << 4) + (l & 15))) & 1u;
      float p = s_acc[nj][r] * inv;
      s_acc[nj][r] = p;
      if (bit) sa += p;
    }
    sadj[r] = sa;
  }
#pragma unroll
  for (int o = 1; o < 16; o <<= 1)
#pragma unroll
    for (int r = 0; r < 4; ++r) sadj[r] += __shfl_xor(sadj[r], o);

  __syncthreads();

#pragma unroll
  for (int r = 0; r < 4; ++r) {
    int i = m0 + ((l >> 4) << 2) + r;
#pragma unroll
    for (int nj = 0; nj < 8; ++nj) {
      int j = nj * 16 + (l & 15);
      Pl[i * 128 + (((j >> 3) ^ (i & 7)) << 3) + (j & 7)] = f2bf(s_acc[nj][r]);
    }
    if ((l & 15) == 0) sL[i] = sadj[r];
  }
  __syncthreads();

  f32x4 o_acc[4];
#pragma unroll
  for (int nj = 0; nj < 4; ++nj) o_acc[nj] = (f32x4){0.f, 0.f, 0.f, 0.f};
#pragma unroll
  for (int kk = 0; kk < 4; ++kk) {
    int prow = m0 + (l & 15);
    int ch = kk * 4 + (l >> 4);
    short8 pa = *(const short8*)&Pl[prow * 128 + ((ch ^ (prow & 7)) << 3)];
#pragma unroll
    for (int nj = 0; nj < 4; ++nj) {
      int vrow = nj * 16 + (l & 15);
      short8 vf = *(const short8*)&VT[vrow * 128 + ((ch ^ (vrow & 7)) << 3)];
      o_acc[nj] = __builtin_amdgcn_mfma_f32_16x16x32_bf16(pa, vf, o_acc[nj], 0, 0, 0);
    }
  }
#pragma unroll
  for (int nj = 0; nj < 4; ++nj)
#pragma unroll
    for (int r = 0; r < 4; ++r) {
      int i = m0 + ((l >> 4) << 2) + r;
      int d = nj * 16 + (l & 15);
      float s = sL[i];
      float v = o_acc[nj][r] + e0s[d] * (1.0f - s) + e1s[d] * s;
      AO[(size_t)(kc * 128 + i) * INNERD + h * DD + d] = f2bf(v);
    }
}

// ===== fused tail: Wo GEMM + gate1 + LN2 + W1 GELU + W2 + gate2 + final add =====
__global__ __launch_bounds__(256) void tail_kernel(const ushort* __restrict__ AO,
                                                   const ushort* __restrict__ WoT,
                                                   const float* __restrict__ bo,
                                                   const ushort* __restrict__ W1T,
                                                   const float* __restrict__ b1,
                                                   const ushort* __restrict__ W2T,
                                                   const float* __restrict__ b2,
                                                   const float* __restrict__ x,
                                                   const int* __restrict__ cl,
                                                   const float* __restrict__ g1,
                                                   const float* __restrict__ g2,
                                                   const float* __restrict__ lng,
                                                   const float* __restrict__ lnb,
                                                   float* __restrict__ out) {
  __shared__ __align__(16) ushort As[32 * 512];   // AO tile; ffh overlays after Wo
  __shared__ __align__(16) ushort Bb[128 * 32];
  __shared__ float tld[32][132];
  __shared__ __align__(16) ushort y2L[32 * 128];
  __shared__ float w0g1[128], w1g1[128], w0g2[128], w1g2[128], lnGs[128], lnBs[128];

  int t = threadIdx.x, w = t >> 6, l = t & 63;
  int m0 = blockIdx.x * 32;
  int wr = (w >> 1) * 16, wc = (w & 1) * 64;

  if (t < 128) {
    w0g1[t] = g1[t] + g1[256 + t]; w1g1[t] = g1[128 + t] - g1[256 + t];
    w0g2[t] = g2[t] + g2[256 + t]; w1g2[t] = g2[128 + t] - g2[256 + t];
  } else {
    lnGs[t - 128] = lng[t - 128]; lnBs[t - 128] = lnb[t - 128];
  }
  for (int c = t; c < 2048; c += 256) {
    int r = c >> 6, ch = c & 63;
    *(uint4*)&As[r * 512 + (((ch & ~7) | ((ch ^ r) & 7)) << 3)] =
        *(const uint4*)&AO[(size_t)(m0 + r) * 512 + ch * 8];
  }
  __syncthreads();

  f32x4 acc[4];
#pragma unroll
  for (int nj = 0; nj < 4; ++nj) acc[nj] = (f32x4){0.f, 0.f, 0.f, 0.f};
  for (int k0 = 0; k0 < 512; k0 += 32) {
#pragma unroll
    for (int i = 0; i < 2; ++i) {
      int c = t + i * 256;
      int r = c >> 2, kc = c & 3;
      *(uint4*)&Bb[r * 32 + kc * 8] = *(const uint4*)&WoT[(size_t)r * 512 + k0 + kc * 8];
    }
    __syncthreads();
    {
      int arow = wr + (l & 15);
      int gch = (k0 >> 3) + (l >> 4);
      short8 aF = *(const short8*)&As[arow * 512 + (((gch & ~7) | ((gch ^ arow) & 7)) << 3)];
#pragma unroll
      for (int nj = 0; nj < 4; ++nj) {
        short8 bF = *(const short8*)&Bb[(wc + nj * 16 + (l & 15)) * 32 + (l >> 4) * 8];
        acc[nj] = __builtin_amdgcn_mfma_f32_16x16x32_bf16(aF, bF, acc[nj], 0, 0, 0);
      }
    }
    __syncthreads();
  }
#pragma unroll
  for (int nj = 0; nj < 4; ++nj)
#pragma unroll
    for (int r = 0; r < 4; ++r) {
      int row = wr + ((l >> 4) << 2) + r;
      int col = wc + nj * 16 + (l & 15);
      tld[row][col] = acc[nj][r] + bo[col];
    }
  __syncthreads();

  int row = t >> 3, part = t & 7;
  int srcn = cl[m0 + row];
  float xv[16], n1r[16];
  {
    const float* xr = x + (size_t)srcn * CC + part * 16;
#pragma unroll
    for (int j = 0; j < 16; ++j) xv[j] = xr[j];
    float dot = 0.f;
#pragma unroll
    for (int j = 0; j < 16; ++j) {
      int c = part * 16 + j;
      dot += tld[row][c] * w0g1[c] + xv[j] * w1g1[c];
    }
    dot += __shfl_xor(dot, 1); dot += __shfl_xor(dot, 2); dot += __shfl_xor(dot, 4);
    float g = 1.0f / (1.0f + __expf(-dot));
    float s = 0.f, q = 0.f;
#pragma unroll
    for (int j = 0; j < 16; ++j) {
      int c = part * 16 + j;
      float nv = tld[row][c] * g + xv[j] * (1.0f - g);
      n1r[j] = nv;
      s += nv; q += nv * nv;
    }
    s += __shfl_xor(s, 1); s += __shfl_xor(s, 2); s += __shfl_xor(s, 4);
    q += __shfl_xor(q, 1); q += __shfl_xor(q, 2); q += __shfl_xor(q, 4);
    float mu = s * (1.0f / CC);
    float var = q * (1.0f / CC) - mu * mu;
    float rs = rsqrtf(var + 1e-5f);
#pragma unroll
    for (int j = 0; j < 16; ++j) {
      int c = part * 16 + j;
      float yv = (n1r[j] - mu) * rs * lnGs[c] + lnBs[c];
      int ch = c >> 3;
      y2L[row * 128 + (((ch & ~7) | ((ch ^ row) & 7)) << 3) + (c & 7)] = f2bf(yv);
    }
  }
  __syncthreads();

  for (int nc = 0; nc < 4; ++nc) {
    f32x4 a1[4];
#pragma unroll
    for (int nj = 0; nj < 4; ++nj) a1[nj] = (f32x4){0.f, 0.f, 0.f, 0.f};
    for (int k0 = 0; k0 < 128; k0 += 32) {
#pragma unroll
      for (int i = 0; i < 2; ++i) {
        int c = t + i * 256;
        int r = c >> 2, kc = c & 3;
        *(uint4*)&Bb[r * 32 + kc * 8] = *(const uint4*)&W1T[(size_t)(nc * 128 + r) * 128 + k0 + kc * 8];
      }
      __syncthreads();
      {
        int arow = wr + (l & 15);
        int gch = (k0 >> 3) + (l >> 4);
        short8 aF = *(const short8*)&y2L[arow * 128 + (((gch & ~7) | ((gch ^ arow) & 7)) << 3)];
#pragma unroll
        for (int nj = 0; nj < 4; ++nj) {
          short8 bF = *(const short8*)&Bb[(wc + nj * 16 + (l & 15)) * 32 + (l >> 4) * 8];
          a1[nj] = __builtin_amdgcn_mfma_f32_16x16x32_bf16(aF, bF, a1[nj], 0, 0, 0);
        }
      }
      __syncthreads();
    }
#pragma unroll
    for (int nj = 0; nj < 4; ++nj)
#pragma unroll
      for (int r = 0; r < 4; ++r) {
        int rw = wr + ((l >> 4) << 2) + r;
        int n = nc * 128 + wc + nj * 16 + (l & 15);
        float v = a1[nj][r] + b1[n];
        v = 0.5f * v * (1.0f + erff(v * 0.70710678118654752f));
        int ch = n >> 3;
        As[rw * 512 + (((ch & ~7) | ((ch ^ rw) & 7)) << 3) + (n & 7)] = f2bf(v);
      }
  }
  __syncthreads();

  f32x4 a2[4];
#pragma unroll
  for (int nj = 0; nj < 4; ++nj) a2[nj] = (f32x4){0.f, 0.f, 0.f, 0.f};
  for (int k0 = 0; k0 < 512; k0 += 32) {
#pragma unroll
    for (int i = 0; i < 2; ++i) {
      int c = t + i * 256;
      int r = c >> 2, kc = c & 3;
      *(uint4*)&Bb[r * 32 + kc * 8] = *(const uint4*)&W2T[(size_t)r * 512 + k0 + kc * 8];
    }
    __syncthreads();
    {
      int arow = wr + (l & 15);
      int gch = (k0 >> 3) + (l >> 4);
      short8 aF = *(const short8*)&As[arow * 512 + (((gch & ~7) | ((gch ^ arow) & 7)) << 3)];
#pragma unroll
      for (int nj = 0; nj < 4; ++nj) {
        short8 bF = *(const short8*)&Bb[(wc + nj * 16 + (l & 15)) * 32 + (l >> 4) * 8];
        a2[nj] = __builtin_amdgcn_mfma_f32_16x16x32_bf16(aF, bF, a2[nj], 0, 0, 0);
      }
    }
    __syncthreads();
  }
#pragma unroll
  for (int nj = 0; nj < 4; ++nj)
#pragma unroll
    for (int r = 0; r < 4; ++r) {
      int rw = wr + ((l >> 4) << 2) + r;
      int col = wc + nj * 16 + (l & 15);
      tld[rw][col] = a2[nj][r] + b2[col];
    }
  __syncthreads();

  {
    float dot = 0.f;
#pragma unroll
    for (int j = 0; j < 16; ++j) {
      int c = part * 16 + j;
      dot += tld[row][c] * w0g2[c] + n1r[j] * w1g2[c];
    }
    dot += __shfl_xor(dot, 1); dot += __shfl_xor(dot, 2); dot += __shfl_xor(dot, 4);
    float g = 1.0f / (1.0f + __expf(-dot));
#pragma unroll
    for (int j = 0; j < 16; ++j) {
      int c = part * 16 + j;
      out[(size_t)srcn * CC + c] = xv[j] + tld[row][c] * g + n1r[j] * (1.0f - g);
    }
  }
}

extern "C" void kernel_launch(void* const* d_in, const int* in_sizes, int n_in,
                              void* d_out, int out_size, void* d_ws, size_t ws_size,
                              hipStream_t stream) {
  const float* x       = (const float*)d_in[0];
  const int*   edge    = (const int*)d_in[1];
  const int*   clusters= (const int*)d_in[2];
  const float* adj_emb = (const float*)d_in[3];
  const float* ln1_g   = (const float*)d_in[4];
  const float* ln1_b   = (const float*)d_in[5];
  const float* Wq      = (const float*)d_in[6];
  const float* bq      = (const float*)d_in[7];
  const float* Wkv     = (const float*)d_in[8];
  const float* bkv     = (const float*)d_in[9];
  const float* We      = (const float*)d_in[10];
  const float* be      = (const float*)d_in[11];
  const float* Wo      = (const float*)d_in[12];
  const float* bo      = (const float*)d_in[13];
  const float* gate1   = (const float*)d_in[14];
  const float* ln2_g   = (const float*)d_in[15];
  const float* ln2_b   = (const float*)d_in[16];
  const float* W1      = (const float*)d_in[17];
  const float* b1      = (const float*)d_in[18];
  const float* W2      = (const float*)d_in[19];
  const float* b2      = (const float*)d_in[20];
  const float* gate2   = (const float*)d_in[21];

  char* wsb = (char*)d_ws;
  unsigned* adjw  = (unsigned*)wsb;                 // 64 KB
  float* e01   = (float*)(wsb + 65536);             // 4 KB
  float* cosF  = (float*)(wsb + 69632);             // 32 KB
  float* sinF  = (float*)(wsb + 102400);            // 32 KB
  ushort* WqkvT= (ushort*)(wsb + 135168);           // 384 KB
  ushort* WoT  = (ushort*)(wsb + 528384);           // 128 KB
  ushort* W1T  = (ushort*)(wsb + 659456);           // 128 KB
  ushort* W2T  = (ushort*)(wsb + 790528);           // 128 KB
  ushort* y    = (ushort*)(wsb + 921600);           // 1 MB
  ushort* P    = (ushort*)(wsb + 1970176);          // 12 MB (4096x1536 bf16)
  ushort* AO   = (ushort*)(wsb + 14553088);         // 4 MB

  pre_kernel<<<1424, 256, 0, stream>>>(Wq, Wkv, Wo, W1, W2, adj_emb, We, be,
                                       x, clusters, ln1_g, ln1_b,
                                       WqkvT, WoT, W1T, W2T, e01, cosF, sinF, adjw, y);
  qkv_adj_kernel<<<640, 256, 0, stream>>>(y, WqkvT, bq, bkv, cosF, sinF, edge, adjw, P);
  // --- instrumentation: attn x3 and tail x3 (idempotent; dur = base + 2*(attn+tail)) ---
  attn_kernel<<<KCL * HH, 512, 0, stream>>>(P, adjw, e01, AO);
  attn_kernel<<<KCL * HH, 512, 0, stream>>>(P, adjw, e01, AO);
  attn_kernel<<<KCL * HH, 512, 0, stream>>>(P, adjw, e01, AO);
  tail_kernel<<<128, 256, 0, stream>>>(AO, WoT, bo, W1T, b1, W2T, b2,
                                       x, clusters, gate1, gate2, ln2_g, ln2_b, (float*)d_out);
  tail_kernel<<<128, 256, 0, stream>>>(AO, WoT, bo, W1T, b1, W2T, b2,
                                       x, clusters, gate1, gate2, ln2_g, ln2_b, (float*)d_out);
  tail_kernel<<<128, 256, 0, stream>>>(AO, WoT, bo, W1T, b1, W2T, b2,
                                       x, clusters, gate1, gate2, ln2_g, ln2_b, (float*)d_out);
}

// Round 7
// 64.988 us; speedup vs baseline: 2.1798x; 2.1798x over previous
//
#include <hip/hip_runtime.h>
#include <math.h>

#define NNODES 4096
#define CC     128
#define KCL    32
#define MM     128
#define EE     65536
#define HH     8
#define DD     64
#define INNERD 512

typedef __attribute__((ext_vector_type(8))) short short8;
typedef __attribute__((ext_vector_type(4))) float f32x4;

__device__ __forceinline__ float bf2f(ushort u) { return __uint_as_float(((unsigned)u) << 16); }
__device__ __forceinline__ ushort f2bf(float f) {
  unsigned b = __float_as_uint(f);
  return (ushort)((b + 0x7FFFu + ((b >> 16) & 1u)) >> 16);
}

// ================= pre: tiled W transposes + e01 + rotary tables + adj zero + LN1 ====
__global__ __launch_bounds__(256) void pre_kernel(const float* __restrict__ Wq,
                                                  const float* __restrict__ Wkv,
                                                  const float* __restrict__ Wo,
                                                  const float* __restrict__ W1,
                                                  const float* __restrict__ W2,
                                                  const float* __restrict__ adj_emb,
                                                  const float* __restrict__ We,
                                                  const float* __restrict__ be,
                                                  const float* __restrict__ x,
                                                  const int* __restrict__ cl,
                                                  const float* __restrict__ ln1g,
                                                  const float* __restrict__ ln1b,
                                                  ushort* __restrict__ WqkvT,
                                                  ushort* __restrict__ WoT,
                                                  ushort* __restrict__ W1T,
                                                  ushort* __restrict__ W2T,
                                                  float* __restrict__ e01,
                                                  float* __restrict__ cosF,
                                                  float* __restrict__ sinF,
                                                  unsigned* __restrict__ adjw,
                                                  ushort* __restrict__ y) {
  __shared__ float lds[32][33];
  int bid = blockIdx.x, t = threadIdx.x;
  if (bid < 384) {
    const float* src; ushort* dst; int N, K, tile;
    if (bid < 64)        { src = Wq;  dst = WqkvT;             N = 512;  K = 128; tile = bid; }
    else if (bid < 192)  { src = Wkv; dst = WqkvT + 512 * 128; N = 1024; K = 128; tile = bid - 64; }
    else if (bid < 256)  { src = Wo;  dst = WoT;               N = 128;  K = 512; tile = bid - 192; }
    else if (bid < 320)  { src = W1;  dst = W1T;               N = 512;  K = 128; tile = bid - 256; }
    else                 { src = W2;  dst = W2T;               N = 128;  K = 512; tile = bid - 320; }
    int tilesN = N >> 5;
    int k0 = (tile / tilesN) << 5, n0 = (tile % tilesN) << 5;
#pragma unroll
    for (int i = 0; i < 4; ++i) {
      int idx = i * 256 + t, kk = idx >> 5, nn = idx & 31;
      lds[kk][nn] = src[(size_t)(k0 + kk) * N + n0 + nn];
    }
    __syncthreads();
#pragma unroll
    for (int i = 0; i < 4; ++i) {
      int idx = i * 256 + t, nn = idx >> 5, kk = idx & 31;
      dst[(size_t)(n0 + nn) * K + k0 + kk] = f2bf(lds[kk][nn]);
    }
  } else if (bid < 388) {
    int idx = (bid - 384) * 256 + t;  // 0..1023
    int which = idx >> 9, col = idx & 511;
    float a = 0.f;
    for (int c = 0; c < CC; ++c) a += adj_emb[which * CC + c] * We[(size_t)c * INNERD + col];
    e01[idx] = a + be[col];
  } else if (bid < 396) {
#pragma unroll
    for (int e = 0; e < 4; ++e) {
      int idx = ((bid - 388) * 256 + t) * 4 + e;  // 0..8191
      int i = idx >> 6, d = idx & 63, p = d >> 1;
      float inv = exp2f(-(float)p * (13.287712379549449f / 32.0f)); // 10000^(-p/32)
      float ang = (float)i * inv;
      cosF[idx] = cosf(ang);
      sinF[idx] = sinf(ang);
    }
  } else if (bid < 400) {
    int base = ((bid - 396) * 256 + t) * 16;
#pragma unroll
    for (int e = 0; e < 16; ++e) adjw[base + e] = 0u;
  } else {
    int row = (bid - 400) * 4 + (t >> 6);
    int lane = t & 63;
    int src = cl[row];
    const float* p = x + (size_t)src * CC;
    float2 v = *(const float2*)(p + lane * 2);
    float s = v.x + v.y, q = v.x * v.x + v.y * v.y;
#pragma unroll
    for (int o = 32; o; o >>= 1) { s += __shfl_xor(s, o); q += __shfl_xor(q, o); }
    float mu = s * (1.0f / CC);
    float var = q * (1.0f / CC) - mu * mu;
    float rs = rsqrtf(var + 1e-5f);
    float2 g2 = *(const float2*)(ln1g + lane * 2);
    float2 b2 = *(const float2*)(ln1b + lane * 2);
    float ox = (v.x - mu) * rs * g2.x + b2.x;
    float oy = (v.y - mu) * rs * g2.y + b2.y;
    *(unsigned*)&y[(size_t)row * CC + lane * 2] = (unsigned)f2bf(ox) | ((unsigned)f2bf(oy) << 16);
  }
}

// ========== QKV GEMM, single-shot K=128 staging + adjacency build ==========
__global__ __launch_bounds__(256) void qkv_adj_kernel(const ushort* __restrict__ A,
                                                      const ushort* __restrict__ BT,
                                                      const float* __restrict__ bq,
                                                      const float* __restrict__ bkv,
                                                      const float* __restrict__ cosF,
                                                      const float* __restrict__ sinF,
                                                      const int* __restrict__ ei,
                                                      unsigned* __restrict__ adjw,
                                                      ushort* __restrict__ P) {
  __shared__ __align__(16) ushort Ab[128 * 128];
  __shared__ __align__(16) ushort Bb[128 * 128];
  int bid = blockIdx.x, t = threadIdx.x;
  if (bid >= 384) {
    int e = (bid - 384) * 256 + t;
    int s = ei[e], d = ei[EE + e];
    int cs = s >> 7, cd = d >> 7;
    if (cs == cd) {
      int flat = cs * (MM * MM) + (s & 127) * MM + (d & 127);
      atomicOr(adjw + (flat >> 5), 1u << (flat & 31));
    }
    return;
  }
  int w = t >> 6, l = t & 63;
  int nt = bid % 12, mt = bid / 12;
  int n0 = nt * 128, m0 = mt * 128;
  int wr = (w >> 1) * 64, wc = (w & 1) * 64;

  // stage full-K tiles, chunk-swizzled (16 chunks/row: sw = (c&8)|((c^r)&7))
#pragma unroll
  for (int i = 0; i < 8; ++i) {
    int c = t + i * 256;
    int r = c >> 4, kc = c & 15;
    int sw = ((kc & 8) | ((kc ^ r) & 7)) << 3;
    *(uint4*)&Ab[r * 128 + sw] = *(const uint4*)&A[(size_t)(m0 + r) * 128 + kc * 8];
    *(uint4*)&Bb[r * 128 + sw] = *(const uint4*)&BT[(size_t)(n0 + r) * 128 + kc * 8];
  }
  __syncthreads();

  f32x4 acc[4][4];
#pragma unroll
  for (int mi = 0; mi < 4; ++mi)
#pragma unroll
    for (int nj = 0; nj < 4; ++nj) acc[mi][nj] = (f32x4){0.f, 0.f, 0.f, 0.f};

#pragma unroll
  for (int kk = 0; kk < 4; ++kk) {
    int gch = kk * 4 + (l >> 4);
    short8 aF[4], bF[4];
#pragma unroll
    for (int mi = 0; mi < 4; ++mi) {
      int row = wr + mi * 16 + (l & 15);
      aF[mi] = *(const short8*)&Ab[row * 128 + (((gch & 8) | ((gch ^ row) & 7)) << 3)];
    }
#pragma unroll
    for (int nj = 0; nj < 4; ++nj) {
      int row = wc + nj * 16 + (l & 15);
      bF[nj] = *(const short8*)&Bb[row * 128 + (((gch & 8) | ((gch ^ row) & 7)) << 3)];
    }
#pragma unroll
    for (int mi = 0; mi < 4; ++mi)
#pragma unroll
      for (int nj = 0; nj < 4; ++nj)
        acc[mi][nj] = __builtin_amdgcn_mfma_f32_16x16x32_bf16(aF[mi], bF[nj], acc[mi][nj], 0, 0, 0);
  }

  // epilogue: bias + rotary + paired dword stores
#pragma unroll
  for (int mi = 0; mi < 4; ++mi)
#pragma unroll
    for (int nj = 0; nj < 4; ++nj)
#pragma unroll
      for (int r = 0; r < 4; ++r) {
        int m = m0 + wr + mi * 16 + ((l >> 4) << 2) + r;
        int n = n0 + wc + nj * 16 + (l & 15);
        float bias = n < 512 ? bq[n] : bkv[n - 512];
        float v = acc[mi][nj][r] + bias;
        float praw = __shfl_xor(v, 1);
        float vr = v;
        if (n < 1024) {
          int d = n & 63, i = m & 127;
          float cv = cosF[i * 64 + d], sv = sinF[i * 64 + d];
          vr = (n & 1) ? (v * cv + praw * sv) : (v * cv - praw * sv);
        }
        float prot = __shfl_xor(vr, 1);
        if ((l & 1) == 0) {
          unsigned pack = (unsigned)f2bf(vr) | ((unsigned)f2bf(prot) << 16);
          *(unsigned*)&P[(size_t)m * 1536 + n] = pack;
        }
      }
}

// ------- fused MFMA attention: 512 blocks x 256 threads, 64 q-rows per block -------
__global__ __launch_bounds__(256) void attn_kernel(const ushort* __restrict__ P,
                                                   const unsigned* __restrict__ adjw,
                                                   const float* __restrict__ e01,
                                                   ushort* __restrict__ AO) {
  __shared__ __align__(16) ushort Qb[64 * 64];    // 8 KB
  __shared__ __align__(16) ushort Kb[128 * 64];   // 16 KB
  __shared__ __align__(16) ushort VT[64 * 128];   // 16 KB
  __shared__ __align__(16) ushort Pl[64 * 128];   // 16 KB
  __shared__ unsigned adjL[256];
  __shared__ float e0s[64], e1s[64], qe0L[64], qe1L[64], sL[64];

  int t = threadIdx.x, w = t >> 6, l = t & 63;
  int bid = blockIdx.x;
  int kc = bid >> 4, h = (bid >> 1) & 7, half = bid & 1;
  int q0 = half * 64;

  const ushort* qg = P + (size_t)kc * 128 * 1536 + h * DD;

  // stage Q (64 rows), K (128), V^T (128 cols)
#pragma unroll
  for (int i = 0; i < 2; ++i) {
    int c = t + i * 256;
    int r = c >> 3, ch = c & 7;
    *(uint4*)&Qb[r * 64 + ((ch ^ (r & 7)) << 3)] = *(const uint4*)&qg[(size_t)(q0 + r) * 1536 + ch * 8];
  }
#pragma unroll
  for (int i = 0; i < 4; ++i) {
    int c = t + i * 256;
    int r = c >> 3, ch = c & 7;
    *(uint4*)&Kb[r * 64 + ((ch ^ (r & 7)) << 3)] = *(const uint4*)&qg[(size_t)r * 1536 + 512 + ch * 8];
    uint4 vv = *(const uint4*)&qg[(size_t)r * 1536 + 1024 + ch * 8];
    const ushort* vp = (const ushort*)&vv;
#pragma unroll
    for (int e = 0; e < 8; ++e) {
      int d = ch * 8 + e;
      VT[d * 128 + (((r >> 3) ^ (d & 7)) << 3) + (r & 7)] = vp[e];
    }
  }
  adjL[t] = adjw[kc * 512 + half * 256 + t];
  if (t < 64) { e0s[t] = e01[h * DD + t]; e1s[t] = e01[512 + h * DD + t]; }
  __syncthreads();

  // qe0/qe1 per local row (64 rows x 4 parts); rows 16w..16w+15 handled by wave w
  {
    int row = t >> 2, part = t & 3;
    float a0 = 0.f, a1 = 0.f;
#pragma unroll
    for (int dd = 0; dd < 16; ++dd) {
      int d = part * 16 + dd;
      float qv = bf2f(Qb[row * 64 + (((d >> 3) ^ (row & 7)) << 3) + (d & 7)]);
      a0 += qv * e0s[d]; a1 += qv * e1s[d];
    }
    a0 += __shfl_xor(a0, 1); a0 += __shfl_xor(a0, 2);
    a1 += __shfl_xor(a1, 1); a1 += __shfl_xor(a1, 2);
    if (part == 0) { qe0L[row] = a0; qe1L[row] = a1; }
  }
  // (no barrier: wave w's QK^T rows == rows it wrote in qe phase; LDS ordering within wave)

  int m0 = w * 16;  // local row tile
  f32x4 s_acc[8];
#pragma unroll
  for (int nj = 0; nj < 8; ++nj) s_acc[nj] = (f32x4){0.f, 0.f, 0.f, 0.f};
  {
    int arow = m0 + (l & 15);
    short8 aF0 = *(const short8*)&Qb[arow * 64 + ((((l >> 4)) ^ (arow & 7)) << 3)];
    short8 aF1 = *(const short8*)&Qb[arow * 64 + (((4 + (l >> 4)) ^ (arow & 7)) << 3)];
#pragma unroll
    for (int nj = 0; nj < 8; ++nj) {
      int brow = nj * 16 + (l & 15);
      short8 b0 = *(const short8*)&Kb[brow * 64 + ((((l >> 4)) ^ (brow & 7)) << 3)];
      short8 b1 = *(const short8*)&Kb[brow * 64 + (((4 + (l >> 4)) ^ (brow & 7)) << 3)];
      s_acc[nj] = __builtin_amdgcn_mfma_f32_16x16x32_bf16(aF0, b0, s_acc[nj], 0, 0, 0);
      s_acc[nj] = __builtin_amdgcn_mfma_f32_16x16x32_bf16(aF1, b1, s_acc[nj], 0, 0, 0);
    }
  }

  // bias + softmax in registers (i = local row)
  float mrow[4], ssum[4], sadj[4];
#pragma unroll
  for (int r = 0; r < 4; ++r) {
    int i = m0 + ((l >> 4) << 2) + r;
    float q0v = qe0L[i], q1v = qe1L[i];
    unsigned w0 = adjL[i * 4 + 0], w1 = adjL[i * 4 + 1], w2 = adjL[i * 4 + 2], w3 = adjL[i * 4 + 3];
    float mx = -1e30f;
#pragma unroll
    for (int nj = 0; nj < 8; ++nj) {
      unsigned word = (nj >> 1) == 0 ? w0 : (nj >> 1) == 1 ? w1 : (nj >> 1) == 2 ? w2 : w3;
      unsigned bit = (word >> (((nj & 1) << 4) + (l & 15))) & 1u;
      float s = (s_acc[nj][r] + (bit ? q1v : q0v)) * 0.125f;
      s_acc[nj][r] = s;
      mx = fmaxf(mx, s);
    }
    mrow[r] = mx;
  }
#pragma unroll
  for (int o = 1; o < 16; o <<= 1)
#pragma unroll
    for (int r = 0; r < 4; ++r) mrow[r] = fmaxf(mrow[r], __shfl_xor(mrow[r], o));
#pragma unroll
  for (int r = 0; r < 4; ++r) {
    float sum = 0.f;
#pragma unroll
    for (int nj = 0; nj < 8; ++nj) {
      float p = __expf(s_acc[nj][r] - mrow[r]);
      s_acc[nj][r] = p;
      sum += p;
    }
    ssum[r] = sum;
  }
#pragma unroll
  for (int o = 1; o < 16; o <<= 1)
#pragma unroll
    for (int r = 0; r < 4; ++r) ssum[r] += __shfl_xor(ssum[r], o);
#pragma unroll
  for (int r = 0; r < 4; ++r) {
    int i = m0 + ((l >> 4) << 2) + r;
    unsigned w0 = adjL[i * 4 + 0], w1 = adjL[i * 4 + 1], w2 = adjL[i * 4 + 2], w3 = adjL[i * 4 + 3];
    float inv = 1.0f / ssum[r];
    float sa = 0.f;
#pragma unroll
    for (int nj = 0; nj < 8; ++nj) {
      int j = nj * 16 + (l & 15);
      unsigned word = (nj >> 1) == 0 ? w0 : (nj >> 1) == 1 ? w1 : (nj >> 1) == 2 ? w2 : w3;
      unsigned bit = (word >> (((nj & 1) << 4) + (l & 15))) & 1u;
      float p = s_acc[nj][r] * inv;
      if (bit) sa += p;
      Pl[i * 128 + (((j >> 3) ^ (i & 7)) << 3) + (j & 7)] = f2bf(p);
    }
    sadj[r] = sa;
  }
#pragma unroll
  for (int o = 1; o < 16; o <<= 1)
#pragma unroll
    for (int r = 0; r < 4; ++r) sadj[r] += __shfl_xor(sadj[r], o);
  if ((l & 15) == 0) {
#pragma unroll
    for (int r = 0; r < 4; ++r) sL[m0 + ((l >> 4) << 2) + r] = sadj[r];
  }
  // (no barrier: PV reads only this wave's Pl/sL rows)

  // PV
  f32x4 o_acc[4];
#pragma unroll
  for (int nj = 0; nj < 4; ++nj) o_acc[nj] = (f32x4){0.f, 0.f, 0.f, 0.f};
#pragma unroll
  for (int kk = 0; kk < 4; ++kk) {
    int prow = m0 + (l & 15);
    int ch = kk * 4 + (l >> 4);
    short8 pa = *(const short8*)&Pl[prow * 128 + ((ch ^ (prow & 7)) << 3)];
#pragma unroll
    for (int nj = 0; nj < 4; ++nj) {
      int vrow = nj * 16 + (l & 15);
      short8 vf = *(const short8*)&VT[vrow * 128 + ((ch ^ (vrow & 7)) << 3)];
      o_acc[nj] = __builtin_amdgcn_mfma_f32_16x16x32_bf16(pa, vf, o_acc[nj], 0, 0, 0);
    }
  }
  // epilogue: paired dword stores
#pragma unroll
  for (int nj = 0; nj < 4; ++nj)
#pragma unroll
    for (int r = 0; r < 4; ++r) {
      int i = m0 + ((l >> 4) << 2) + r;
      int d = nj * 16 + (l & 15);
      float s = sL[i];
      float v = o_acc[nj][r] + e0s[d] * (1.0f - s) + e1s[d] * s;
      float pv = __shfl_xor(v, 1);
      if ((l & 1) == 0) {
        unsigned pack = (unsigned)f2bf(v) | ((unsigned)f2bf(pv) << 16);
        *(unsigned*)&AO[(size_t)(kc * 128 + half * 64 + i) * INNERD + h * DD + d] = pack;
      }
    }
}

// ===== fused tail: 256 blocks x 16 rows; BK=128, double-buffered B staging =====
__device__ __forceinline__ void tail_stage(int s, ushort* __restrict__ buf, int t,
                                           const ushort* __restrict__ WoT,
                                           const ushort* __restrict__ W1T,
                                           const ushort* __restrict__ W2T) {
#pragma unroll
  for (int i = 0; i < 8; ++i) {
    int c = t + i * 256;
    int r = c >> 4, kc = c & 15;
    const ushort* p;
    if (s < 4)      p = &WoT[(size_t)r * 512 + s * 128 + kc * 8];
    else if (s < 8) p = &W1T[(size_t)((s - 4) * 128 + r) * 128 + kc * 8];
    else            p = &W2T[(size_t)r * 512 + (s - 8) * 128 + kc * 8];
    *(uint4*)&buf[r * 128 + (((kc & 8) | ((kc ^ r) & 7)) << 3)] = *(const uint4*)p;
  }
}

__global__ __launch_bounds__(256) void tail_kernel(const ushort* __restrict__ AO,
                                                   const ushort* __restrict__ WoT,
                                                   const float* __restrict__ bo,
                                                   const ushort* __restrict__ W1T,
                                                   const float* __restrict__ b1,
                                                   const ushort* __restrict__ W2T,
                                                   const float* __restrict__ b2,
                                                   const float* __restrict__ x,
                                                   const int* __restrict__ cl,
                                                   const float* __restrict__ g1,
                                                   const float* __restrict__ g2,
                                                   const float* __restrict__ lng,
                                                   const float* __restrict__ lnb,
                                                   float* __restrict__ out) {
  __shared__ __align__(16) ushort As[16 * 512];        // AO tile; ffh overlays after Wo
  __shared__ __align__(16) ushort Bb[2][128 * 128];    // 64 KB dbuf
  __shared__ float tld[16][132];
  __shared__ __align__(16) ushort y2L[16 * 128];
  __shared__ float w0g1[128], w1g1[128], w0g2[128], w1g2[128], lnGs[128], lnBs[128];

  int t = threadIdx.x, w = t >> 6, l = t & 63;
  int m0 = blockIdx.x * 16;

  if (t < 128) {
    w0g1[t] = g1[t] + g1[256 + t]; w1g1[t] = g1[128 + t] - g1[256 + t];
    w0g2[t] = g2[t] + g2[256 + t]; w1g2[t] = g2[128 + t] - g2[256 + t];
  } else {
    lnGs[t - 128] = lng[t - 128]; lnBs[t - 128] = lnb[t - 128];
  }
  // stage AO tile (16 rows x 64 chunks)
#pragma unroll
  for (int i = 0; i < 4; ++i) {
    int c = t + i * 256;
    int r = c >> 6, ch = c & 63;
    *(uint4*)&As[r * 512 + (((ch & ~7) | ((ch ^ r) & 7)) << 3)] =
        *(const uint4*)&AO[(size_t)(m0 + r) * 512 + ch * 8];
  }
  tail_stage(0, Bb[0], t, WoT, W1T, W2T);
  __syncthreads();

  int arow = l & 15;

  // ---- Wo: 4 wide steps, acc across steps ----
  f32x4 aWo[2];
  aWo[0] = (f32x4){0.f, 0.f, 0.f, 0.f}; aWo[1] = (f32x4){0.f, 0.f, 0.f, 0.f};
  for (int s = 0; s < 4; ++s) {
    tail_stage(s + 1, Bb[(s + 1) & 1], t, WoT, W1T, W2T);
    ushort* buf = Bb[s & 1];
#pragma unroll
    for (int kk = 0; kk < 4; ++kk) {
      int gA = s * 16 + kk * 4 + (l >> 4);
      short8 aF = *(const short8*)&As[arow * 512 + (((gA & ~7) | ((gA ^ arow) & 7)) << 3)];
      int gB = kk * 4 + (l >> 4);
#pragma unroll
      for (int nj = 0; nj < 2; ++nj) {
        int brow = w * 32 + nj * 16 + (l & 15);
        short8 bF = *(const short8*)&buf[brow * 128 + (((gB & 8) | ((gB ^ brow) & 7)) << 3)];
        aWo[nj] = __builtin_amdgcn_mfma_f32_16x16x32_bf16(aF, bF, aWo[nj], 0, 0, 0);
      }
    }
    __syncthreads();
  }
#pragma unroll
  for (int nj = 0; nj < 2; ++nj)
#pragma unroll
    for (int r = 0; r < 4; ++r) {
      int row = ((l >> 4) << 2) + r;
      int col = w * 32 + nj * 16 + (l & 15);
      tld[row][col] = aWo[nj][r] + bo[col];
    }
  __syncthreads();

  // ---- gate1 + LN2 (16 threads/row, 8 cols each); n1 kept in registers ----
  int row = t >> 4, part = t & 15;
  int srcn = cl[m0 + row];
  float xv[8], n1r[8];
  {
    const float* xr = x + (size_t)srcn * CC + part * 8;
    float4 xa = *(const float4*)xr, xb = *(const float4*)(xr + 4);
    xv[0] = xa.x; xv[1] = xa.y; xv[2] = xa.z; xv[3] = xa.w;
    xv[4] = xb.x; xv[5] = xb.y; xv[6] = xb.z; xv[7] = xb.w;
    float dot = 0.f;
#pragma unroll
    for (int j = 0; j < 8; ++j) {
      int c = part * 8 + j;
      dot += tld[row][c] * w0g1[c] + xv[j] * w1g1[c];
    }
    dot += __shfl_xor(dot, 1); dot += __shfl_xor(dot, 2);
    dot += __shfl_xor(dot, 4); dot += __shfl_xor(dot, 8);
    float g = 1.0f / (1.0f + __expf(-dot));
    float s = 0.f, q = 0.f;
#pragma unroll
    for (int j = 0; j < 8; ++j) {
      int c = part * 8 + j;
      float nv = tld[row][c] * g + xv[j] * (1.0f - g);
      n1r[j] = nv;
      s += nv; q += nv * nv;
    }
    s += __shfl_xor(s, 1); s += __shfl_xor(s, 2); s += __shfl_xor(s, 4); s += __shfl_xor(s, 8);
    q += __shfl_xor(q, 1); q += __shfl_xor(q, 2); q += __shfl_xor(q, 4); q += __shfl_xor(q, 8);
    float mu = s * (1.0f / CC);
    float var = q * (1.0f / CC) - mu * mu;
    float rs = rsqrtf(var + 1e-5f);
    float yv[8];
#pragma unroll
    for (int j = 0; j < 8; ++j) {
      int c = part * 8 + j;
      yv[j] = (n1r[j] - mu) * rs * lnGs[c] + lnBs[c];
    }
    uint4 pk;
    pk.x = (unsigned)f2bf(yv[0]) | ((unsigned)f2bf(yv[1]) << 16);
    pk.y = (unsigned)f2bf(yv[2]) | ((unsigned)f2bf(yv[3]) << 16);
    pk.z = (unsigned)f2bf(yv[4]) | ((unsigned)f2bf(yv[5]) << 16);
    pk.w = (unsigned)f2bf(yv[6]) | ((unsigned)f2bf(yv[7]) << 16);
    *(uint4*)&y2L[row * 128 + (((part & 8) | ((part ^ row) & 7)) << 3)] = pk;
  }
  __syncthreads();

  // ---- W1 + GELU: 4 wide steps (one per nc), ffh overlays As ----
  for (int s = 4; s < 8; ++s) {
    tail_stage(s + 1, Bb[(s + 1) & 1], t, WoT, W1T, W2T);
    ushort* buf = Bb[s & 1];
    f32x4 a1[2];
    a1[0] = (f32x4){0.f, 0.f, 0.f, 0.f}; a1[1] = (f32x4){0.f, 0.f, 0.f, 0.f};
#pragma unroll
    for (int kk = 0; kk < 4; ++kk) {
      int g = kk * 4 + (l >> 4);
      short8 aF = *(const short8*)&y2L[arow * 128 + (((g & 8) | ((g ^ arow) & 7)) << 3)];
#pragma unroll
      for (int nj = 0; nj < 2; ++nj) {
        int brow = w * 32 + nj * 16 + (l & 15);
        short8 bF = *(const short8*)&buf[brow * 128 + (((g & 8) | ((g ^ brow) & 7)) << 3)];
        a1[nj] = __builtin_amdgcn_mfma_f32_16x16x32_bf16(aF, bF, a1[nj], 0, 0, 0);
      }
    }
#pragma unroll
    for (int nj = 0; nj < 2; ++nj)
#pragma unroll
      for (int r = 0; r < 4; ++r) {
        int rw = ((l >> 4) << 2) + r;
        int n = (s - 4) * 128 + w * 32 + nj * 16 + (l & 15);
        float v = a1[nj][r] + b1[n];
        v = 0.5f * v * (1.0f + erff(v * 0.70710678118654752f));
        int ch = n >> 3;
        As[rw * 512 + (((ch & ~7) | ((ch ^ rw) & 7)) << 3) + (n & 7)] = f2bf(v);
      }
    __syncthreads();
  }

  // ---- W2: 4 wide steps, acc across steps ----
  f32x4 aW2[2];
  aW2[0] = (f32x4){0.f, 0.f, 0.f, 0.f}; aW2[1] = (f32x4){0.f, 0.f, 0.f, 0.f};
  for (int s = 8; s < 12; ++s) {
    if (s < 11) tail_stage(s + 1, Bb[(s + 1) & 1], t, WoT, W1T, W2T);
    ushort* buf = Bb[s & 1];
#pragma unroll
    for (int kk = 0; kk < 4; ++kk) {
      int gA = (s - 8) * 16 + kk * 4 + (l >> 4);
      short8 aF = *(const short8*)&As[arow * 512 + (((gA & ~7) | ((gA ^ arow) & 7)) << 3)];
      int gB = kk * 4 + (l >> 4);
#pragma unroll
      for (int nj = 0; nj < 2; ++nj) {
        int brow = w * 32 + nj * 16 + (l & 15);
        short8 bF = *(const short8*)&buf[brow * 128 + (((gB & 8) | ((gB ^ brow) & 7)) << 3)];
        aW2[nj] = __builtin_amdgcn_mfma_f32_16x16x32_bf16(aF, bF, aW2[nj], 0, 0, 0);
      }
    }
    __syncthreads();
  }
#pragma unroll
  for (int nj = 0; nj < 2; ++nj)
#pragma unroll
    for (int r = 0; r < 4; ++r) {
      int rw = ((l >> 4) << 2) + r;
      int col = w * 32 + nj * 16 + (l & 15);
      tld[rw][col] = aW2[nj][r] + b2[col];
    }
  __syncthreads();

  // ---- gate2 + final add ----
  {
    float dot = 0.f;
#pragma unroll
    for (int j = 0; j < 8; ++j) {
      int c = part * 8 + j;
      dot += tld[row][c] * w0g2[c] + n1r[j] * w1g2[c];
    }
    dot += __shfl_xor(dot, 1); dot += __shfl_xor(dot, 2);
    dot += __shfl_xor(dot, 4); dot += __shfl_xor(dot, 8);
    float g = 1.0f / (1.0f + __expf(-dot));
    float4 o1, o2;
    float* o1p = (float*)&o1; float* o2p = (float*)&o2;
#pragma unroll
    for (int j = 0; j < 4; ++j) {
      int c = part * 8 + j;
      o1p[j] = xv[j] + tld[row][c] * g + n1r[j] * (1.0f - g);
    }
#pragma unroll
    for (int j = 4; j < 8; ++j) {
      int c = part * 8 + j;
      o2p[j - 4] = xv[j] + tld[row][c] * g + n1r[j] * (1.0f - g);
    }
    float* op = out + (size_t)srcn * CC + part * 8;
    *(float4*)op = o1;
    *(float4*)(op + 4) = o2;
  }
}

extern "C" void kernel_launch(void* const* d_in, const int* in_sizes, int n_in,
                              void* d_out, int out_size, void* d_ws, size_t ws_size,
                              hipStream_t stream) {
  const float* x       = (const float*)d_in[0];
  const int*   edge    = (const int*)d_in[1];
  const int*   clusters= (const int*)d_in[2];
  const float* adj_emb = (const float*)d_in[3];
  const float* ln1_g   = (const float*)d_in[4];
  const float* ln1_b   = (const float*)d_in[5];
  const float* Wq      = (const float*)d_in[6];
  const float* bq      = (const float*)d_in[7];
  const float* Wkv     = (const float*)d_in[8];
  const float* bkv     = (const float*)d_in[9];
  const float* We      = (const float*)d_in[10];
  const float* be      = (const float*)d_in[11];
  const float* Wo      = (const float*)d_in[12];
  const float* bo      = (const float*)d_in[13];
  const float* gate1   = (const float*)d_in[14];
  const float* ln2_g   = (const float*)d_in[15];
  const float* ln2_b   = (const float*)d_in[16];
  const float* W1      = (const float*)d_in[17];
  const float* b1      = (const float*)d_in[18];
  const float* W2      = (const float*)d_in[19];
  const float* b2      = (const float*)d_in[20];
  const float* gate2   = (const float*)d_in[21];

  char* wsb = (char*)d_ws;
  unsigned* adjw  = (unsigned*)wsb;                 // 64 KB
  float* e01   = (float*)(wsb + 65536);             // 4 KB
  float* cosF  = (float*)(wsb + 69632);             // 32 KB
  float* sinF  = (float*)(wsb + 102400);            // 32 KB
  ushort* WqkvT= (ushort*)(wsb + 135168);           // 384 KB
  ushort* WoT  = (ushort*)(wsb + 528384);           // 128 KB
  ushort* W1T  = (ushort*)(wsb + 659456);           // 128 KB
  ushort* W2T  = (ushort*)(wsb + 790528);           // 128 KB
  ushort* y    = (ushort*)(wsb + 921600);           // 1 MB
  ushort* P    = (ushort*)(wsb + 1970176);          // 12 MB (4096x1536 bf16)
  ushort* AO   = (ushort*)(wsb + 14553088);         // 4 MB

  pre_kernel<<<1424, 256, 0, stream>>>(Wq, Wkv, Wo, W1, W2, adj_emb, We, be,
                                       x, clusters, ln1_g, ln1_b,
                                       WqkvT, WoT, W1T, W2T, e01, cosF, sinF, adjw, y);
  qkv_adj_kernel<<<640, 256, 0, stream>>>(y, WqkvT, bq, bkv, cosF, sinF, edge, adjw, P);
  attn_kernel<<<512, 256, 0, stream>>>(P, adjw, e01, AO);
  tail_kernel<<<256, 256, 0, stream>>>(AO, WoT, bo, W1T, b1, W2T, b2,
                                       x, clusters, gate1, gate2, ln2_g, ln2_b, (float*)d_out);
}